// Round 1
// baseline (390.380 us; speedup 1.0000x reference)
//
#include <hip/hip_runtime.h>

// Problem geometry: B=4, H=W=32, C=256. Per sample, 2 orientations (lr, tb),
// each a corr-recon on a (31x32)/(32x31) grid, L=992 locations.
// Task t in [0,8): s = t>>1 (sample), o = t&1 (0=lr, 1=tb).
//
// Algebra: with M = a*b (elementwise, per-pixel), S = M M^T (LxL),
//   G[l1,l2] = sum_{d in 3x3} S[l1+d, l2+d]   (both shifted, OOB -> 0)
//   logits   = 10 * G * inv[l1] * inv[l2],  P = softmax_rows(logits)
//   W[m,l']  = sum_{d in 3x3} P[m-d, l'-d]    (both shifted, OOB -> 0)
//   ya = W @ A, yb = W @ B  (one GEMM: Y = W @ [A|B], L x 512)

constexpr int NL  = 992;
constexpr int NC  = 256;
constexpr int NC2 = 512;
constexpr int NLL  = NL * NL;    // 984064
constexpr int NLC2 = NL * NC2;   // 507904
// per-task float offsets in workspace
constexpr int OFF_AB  = 0;                   // L x 512  (A | B)
constexpr int OFF_S   = NLC2;                // L x L    (S, later reused for W)
constexpr int OFF_P   = NLC2 + NLL;          // L x L    (P)
constexpr int OFF_Y   = NLC2 + 2 * NLL;      // L x 512  (M occupies first LxC, later Y)
constexpr int OFF_SA  = 2 * NLC2 + 2 * NLL;  // L  per-pixel |a|^2
constexpr int OFF_SB  = OFF_SA + 1024;       // L  per-pixel |b|^2
constexpr int OFF_INV = OFF_SA + 2048;       // L  1/(max(na,eps)*max(nb,eps))
constexpr int TSTRIDE = OFF_SA + 3072;       // 2987008 floats/task -> ~95.6 MB total

// ---------------- K1: build A|B, M, per-pixel squared norms ----------------
__global__ __launch_bounds__(256) void k_prep(const float* __restrict__ x,
                                              float* __restrict__ ws) {
    const int blk = blockIdx.x;       // t*NL + l
    const int t = blk / NL;
    const int l = blk - t * NL;
    const int s = t >> 1, o = t & 1;
    int aoff, boff;
    if (o == 0) {  // lr: grid (31,32); a = x[s, lh, lw], b = x[s, lh+1, lw]
        const int lh = l >> 5, lw = l & 31;
        aoff = ((s * 32 + lh) * 32 + lw) * NC;
        boff = ((s * 32 + lh + 1) * 32 + lw) * NC;
    } else {       // tb: grid (32,31); a = x[s, lh, lw+1], b = x[s, lh, lw]
        const int lh = l / 31, lw = l - lh * 31;
        aoff = ((s * 32 + lh) * 32 + lw + 1) * NC;
        boff = ((s * 32 + lh) * 32 + lw) * NC;
    }
    float* wst = ws + (size_t)t * TSTRIDE;
    const int c = threadIdx.x;
    const float av = x[aoff + c];
    const float bv = x[boff + c];
    wst[OFF_AB + l * NC2 + c] = av;
    wst[OFF_AB + l * NC2 + NC + c] = bv;
    wst[OFF_Y + l * NC + c] = av * bv;   // M
    float ra = av * av, rb = bv * bv;
#pragma unroll
    for (int off = 32; off > 0; off >>= 1) {
        ra += __shfl_down(ra, off);
        rb += __shfl_down(rb, off);
    }
    __shared__ float shA[4], shB[4];
    const int wave = threadIdx.x >> 6, lane = threadIdx.x & 63;
    if (lane == 0) { shA[wave] = ra; shB[wave] = rb; }
    __syncthreads();
    if (threadIdx.x == 0) {
        wst[OFF_SA + l] = shA[0] + shA[1] + shA[2] + shA[3];
        wst[OFF_SB + l] = shB[0] + shB[1] + shB[2] + shB[3];
    }
}

// ---------------- K2: patch norms via 3x3 box sum -> inv ----------------
__global__ __launch_bounds__(1024) void k_inv(float* __restrict__ ws) {
    const int t = blockIdx.x;
    const int l = threadIdx.x;
    if (l >= NL) return;
    const int o = t & 1;
    const int Hp = o ? 32 : 31, Wp = o ? 31 : 32;
    float* wst = ws + (size_t)t * TSTRIDE;
    const int h = l / Wp, w = l - h * Wp;
    float na2 = 0.0f, nb2 = 0.0f;
#pragma unroll
    for (int dh = -1; dh <= 1; ++dh)
#pragma unroll
        for (int dw = -1; dw <= 1; ++dw) {
            const int hh = h + dh, ww = w + dw;
            if ((unsigned)hh < (unsigned)Hp && (unsigned)ww < (unsigned)Wp) {
                const int ll = hh * Wp + ww;
                na2 += wst[OFF_SA + ll];
                nb2 += wst[OFF_SB + ll];
            }
        }
    const float na = fmaxf(sqrtf(na2), 1e-4f);
    const float nb = fmaxf(sqrtf(nb2), 1e-4f);
    wst[OFF_INV + l] = 1.0f / (na * nb);
}

// ---------------- K3: S = M @ M^T  (992x992, K=256), fp32 tiled ----------------
__global__ __launch_bounds__(256) void k_gram(float* __restrict__ ws) {
    const int t = blockIdx.z;
    float* wst = ws + (size_t)t * TSTRIDE;
    const float* __restrict__ M = wst + OFF_Y;
    float* __restrict__ S = wst + OFF_S;
    __shared__ float As[64][17];
    __shared__ float Bs[64][17];
    const int tx = threadIdx.x & 15, ty = threadIdx.x >> 4;
    const int i0 = blockIdx.y * 64, j0 = blockIdx.x * 64;
    const int lr = threadIdx.x >> 2;
    const int lk = (threadIdx.x & 3) * 4;
    float acc[4][4] = {};
    for (int k0 = 0; k0 < NC; k0 += 16) {
        float4 a4 = make_float4(0.f, 0.f, 0.f, 0.f);
        float4 b4 = make_float4(0.f, 0.f, 0.f, 0.f);
        if (i0 + lr < NL) a4 = *(const float4*)(M + (i0 + lr) * NC + k0 + lk);
        if (j0 + lr < NL) b4 = *(const float4*)(M + (j0 + lr) * NC + k0 + lk);
        __syncthreads();
        As[lr][lk + 0] = a4.x; As[lr][lk + 1] = a4.y; As[lr][lk + 2] = a4.z; As[lr][lk + 3] = a4.w;
        Bs[lr][lk + 0] = b4.x; Bs[lr][lk + 1] = b4.y; Bs[lr][lk + 2] = b4.z; Bs[lr][lk + 3] = b4.w;
        __syncthreads();
#pragma unroll
        for (int kk = 0; kk < 16; ++kk) {
            float a[4], b[4];
#pragma unroll
            for (int ii = 0; ii < 4; ++ii) a[ii] = As[ty * 4 + ii][kk];
#pragma unroll
            for (int jj = 0; jj < 4; ++jj) b[jj] = Bs[tx * 4 + jj][kk];
#pragma unroll
            for (int ii = 0; ii < 4; ++ii)
#pragma unroll
                for (int jj = 0; jj < 4; ++jj)
                    acc[ii][jj] = fmaf(a[ii], b[jj], acc[ii][jj]);
        }
    }
#pragma unroll
    for (int ii = 0; ii < 4; ++ii) {
        const int i = i0 + ty * 4 + ii;
        const int j = j0 + tx * 4;
        if (i < NL && j < NL) {
            *(float4*)(S + i * NL + j) =
                make_float4(acc[ii][0], acc[ii][1], acc[ii][2], acc[ii][3]);
        }
    }
}

// ---------------- K4: G (9-shift band sum of S) -> scaled logits -> softmax row -> P ----
__global__ __launch_bounds__(256) void k_softmax(float* __restrict__ ws) {
    const int blk = blockIdx.x;       // t*NL + l1
    const int t = blk / NL;
    const int l1 = blk - t * NL;
    const int o = t & 1;
    const int Hp = o ? 32 : 31, Wp = o ? 31 : 32;
    float* wst = ws + (size_t)t * TSTRIDE;
    const float* __restrict__ S = wst + OFF_S;
    const float* __restrict__ inv = wst + OFF_INV;
    float* __restrict__ P = wst + OFF_P;
    const int h1 = l1 / Wp, w1 = l1 - h1 * Wp;
    const float inv1 = inv[l1] * 10.0f;
    float lg[4];
    float mx = -3.0e38f;
#pragma unroll
    for (int j = 0; j < 4; ++j) {
        const int l2 = threadIdx.x + j * 256;
        if (l2 < NL) {
            const int h2 = l2 / Wp, w2 = l2 - h2 * Wp;
            float G = 0.0f;
#pragma unroll
            for (int dh = -1; dh <= 1; ++dh)
#pragma unroll
                for (int dw = -1; dw <= 1; ++dw) {
                    const bool ok = (unsigned)(h1 + dh) < (unsigned)Hp &&
                                    (unsigned)(w1 + dw) < (unsigned)Wp &&
                                    (unsigned)(h2 + dh) < (unsigned)Hp &&
                                    (unsigned)(w2 + dw) < (unsigned)Wp;
                    if (ok) {
                        const int d = dh * Wp + dw;
                        G += S[(l1 + d) * NL + (l2 + d)];
                    }
                }
            lg[j] = G * inv1 * inv[l2];
            mx = fmaxf(mx, lg[j]);
        } else {
            lg[j] = -3.0e38f;
        }
    }
    __shared__ float red[4];
    const int wave = threadIdx.x >> 6, lane = threadIdx.x & 63;
#pragma unroll
    for (int off = 32; off > 0; off >>= 1) mx = fmaxf(mx, __shfl_down(mx, off));
    if (lane == 0) red[wave] = mx;
    __syncthreads();
    mx = fmaxf(fmaxf(red[0], red[1]), fmaxf(red[2], red[3]));
    __syncthreads();
    float e[4];
    float sum = 0.0f;
#pragma unroll
    for (int j = 0; j < 4; ++j) {
        const int l2 = threadIdx.x + j * 256;
        e[j] = __expf(lg[j] - mx);
        if (l2 < NL) sum += e[j];
    }
#pragma unroll
    for (int off = 32; off > 0; off >>= 1) sum += __shfl_down(sum, off);
    if (lane == 0) red[wave] = sum;
    __syncthreads();
    sum = red[0] + red[1] + red[2] + red[3];
    const float rs = 1.0f / sum;
#pragma unroll
    for (int j = 0; j < 4; ++j) {
        const int l2 = threadIdx.x + j * 256;
        if (l2 < NL) P[l1 * NL + l2] = e[j] * rs;
    }
}

// ---------------- K5: W = 9-shift band sum of P (into S buffer) ----------------
__global__ __launch_bounds__(256) void k_blur(float* __restrict__ ws) {
    const int blk = blockIdx.x;       // t*NL + m
    const int t = blk / NL;
    const int m = blk - t * NL;
    const int o = t & 1;
    const int Hp = o ? 32 : 31, Wp = o ? 31 : 32;
    float* wst = ws + (size_t)t * TSTRIDE;
    const float* __restrict__ P = wst + OFF_P;
    float* __restrict__ Wb = wst + OFF_S;
    const int hm = m / Wp, wm = m - hm * Wp;
#pragma unroll
    for (int j = 0; j < 4; ++j) {
        const int lp = threadIdx.x + j * 256;
        if (lp < NL) {
            const int hp = lp / Wp, wp = lp - hp * Wp;
            float acc = 0.0f;
#pragma unroll
            for (int dh = -1; dh <= 1; ++dh)
#pragma unroll
                for (int dw = -1; dw <= 1; ++dw) {
                    const bool ok = (unsigned)(hm - dh) < (unsigned)Hp &&
                                    (unsigned)(wm - dw) < (unsigned)Wp &&
                                    (unsigned)(hp - dh) < (unsigned)Hp &&
                                    (unsigned)(wp - dw) < (unsigned)Wp;
                    if (ok) {
                        const int d = dh * Wp + dw;
                        acc += P[(m - d) * NL + (lp - d)];
                    }
                }
            Wb[m * NL + lp] = acc;
        }
    }
}

// ---------------- K6: Y = W @ [A|B]  (992 x 512, K=992), fp32 tiled ----------------
__global__ __launch_bounds__(256) void k_recon(float* __restrict__ ws) {
    const int t = blockIdx.z;
    float* wst = ws + (size_t)t * TSTRIDE;
    const float* __restrict__ Wm = wst + OFF_S;
    const float* __restrict__ AB = wst + OFF_AB;
    float* __restrict__ Y = wst + OFF_Y;
    __shared__ float As[64][17];
    __shared__ float Bs[16][64];
    const int tx = threadIdx.x & 15, ty = threadIdx.x >> 4;
    const int i0 = blockIdx.y * 64, j0 = blockIdx.x * 64;
    const int lr = threadIdx.x >> 2;
    const int lk = (threadIdx.x & 3) * 4;
    const int br = threadIdx.x >> 4;          // 0..15 (k row)
    const int bc = (threadIdx.x & 15) * 4;    // 0..60 (n col)
    float acc[4][4] = {};
    for (int k0 = 0; k0 < NL; k0 += 16) {     // 62 exact iterations
        float4 a4 = make_float4(0.f, 0.f, 0.f, 0.f);
        if (i0 + lr < NL) a4 = *(const float4*)(Wm + (i0 + lr) * NL + k0 + lk);
        const float4 b4 = *(const float4*)(AB + (k0 + br) * NC2 + j0 + bc);
        __syncthreads();
        As[lr][lk + 0] = a4.x; As[lr][lk + 1] = a4.y; As[lr][lk + 2] = a4.z; As[lr][lk + 3] = a4.w;
        *(float4*)(&Bs[br][bc]) = b4;
        __syncthreads();
#pragma unroll
        for (int kk = 0; kk < 16; ++kk) {
            float a[4], b[4];
#pragma unroll
            for (int ii = 0; ii < 4; ++ii) a[ii] = As[ty * 4 + ii][kk];
#pragma unroll
            for (int jj = 0; jj < 4; ++jj) b[jj] = Bs[kk][tx * 4 + jj];
#pragma unroll
            for (int ii = 0; ii < 4; ++ii)
#pragma unroll
                for (int jj = 0; jj < 4; ++jj)
                    acc[ii][jj] = fmaf(a[ii], b[jj], acc[ii][jj]);
        }
    }
#pragma unroll
    for (int ii = 0; ii < 4; ++ii) {
        const int i = i0 + ty * 4 + ii;
        if (i < NL) {
            *(float4*)(Y + i * NC2 + j0 + tx * 4) =
                make_float4(acc[ii][0], acc[ii][1], acc[ii][2], acc[ii][3]);
        }
    }
}

// ---------------- K7: seam combine -> out ----------------
__global__ __launch_bounds__(256) void k_combine(float* __restrict__ out,
                                                 const float* __restrict__ ws) {
    const int idx = blockIdx.x;          // s*1024 + h*32 + w
    const int s = idx >> 10;
    const int hw = idx & 1023;
    const int h = hw >> 5, w = hw & 31;
    const int c = threadIdx.x;
    const float* Ylr = ws + (size_t)(2 * s) * TSTRIDE + OFF_Y;
    const float* Ytb = ws + (size_t)(2 * s + 1) * TSTRIDE + OFF_Y;
    float v = 0.0f;
    // ylr: yl = a-recon (ch 0..255), yr = b-recon (ch 256..511), lr grid Wp=32
    if (h < 31) v += Ylr[(h * 32 + w) * NC2 + NC + c] * (h == 0 ? 1.0f : 0.5f);
    if (h >= 1) v += Ylr[((h - 1) * 32 + w) * NC2 + c] * (h == 31 ? 1.0f : 0.5f);
    // ytb: yt = a-recon (ch 0..255), yb = b-recon (ch 256..511), tb grid Wp=31
    if (w < 31) v += Ytb[(h * 31 + w) * NC2 + c] * (w == 0 ? 1.0f : 0.5f);
    if (w >= 1) v += Ytb[(h * 31 + (w - 1)) * NC2 + NC + c] * (w == 31 ? 1.0f : 0.5f);
    out[(size_t)idx * NC + c] = v * 0.5f;
}

extern "C" void kernel_launch(void* const* d_in, const int* in_sizes, int n_in,
                              void* d_out, int out_size, void* d_ws, size_t ws_size,
                              hipStream_t stream) {
    const float* x = (const float*)d_in[0];   // (4,32,32,256) f32; mask (d_in[1]) unused
    float* out = (float*)d_out;               // (4,32,32,256) f32
    float* ws = (float*)d_ws;                 // needs 8*TSTRIDE*4 = ~95.6 MB

    hipLaunchKernelGGL(k_prep,    dim3(8 * NL),      dim3(256),  0, stream, x, ws);
    hipLaunchKernelGGL(k_inv,     dim3(8),           dim3(1024), 0, stream, ws);
    hipLaunchKernelGGL(k_gram,    dim3(16, 16, 8),   dim3(256),  0, stream, ws);
    hipLaunchKernelGGL(k_softmax, dim3(8 * NL),      dim3(256),  0, stream, ws);
    hipLaunchKernelGGL(k_blur,    dim3(8 * NL),      dim3(256),  0, stream, ws);
    hipLaunchKernelGGL(k_recon,   dim3(8, 16, 8),    dim3(256),  0, stream, ws);
    hipLaunchKernelGGL(k_combine, dim3(4096),        dim3(256),  0, stream, out, ws);
}

// Round 2
// 218.257 us; speedup vs baseline: 1.7886x; 1.7886x over previous
//
#include <hip/hip_runtime.h>

// B=4, H=W=32, C=256. 8 tasks (sample x orientation), grid L=992 each.
// Pipeline per task: Mh=f16(a*b) -> S = Mh Mh^T (MFMA f16, fp32 out)
//   G = 9-shift band sum of S -> softmax -> Ph (f16)
//   Wh = 9-shift band sum of Ph (f16)
//   Y = Wh @ ABt^T (MFMA f16, fp32 out) -> seam combine.

typedef _Float16 half8 __attribute__((ext_vector_type(8)));
typedef _Float16 half4h __attribute__((ext_vector_type(4)));
typedef float floatx4 __attribute__((ext_vector_type(4)));

constexpr int NL = 992, NC = 256, NC2 = 512;
constexpr int NLL = NL * NL;
// float-granular offsets in workspace (per task)
constexpr int OFF_S   = 0;                    // f32 [992][992]
constexpr int OFF_Y   = NLL;                  // f32 [992][512]
constexpr int OFF_PH  = NLL + NL * NC2;       // f16 [992][992]
constexpr int OFF_WH  = OFF_PH + NLL / 2;     // f16 [992][992]
constexpr int OFF_ABT = OFF_WH + NLL / 2;     // f16 [512][992]
constexpr int OFF_MH  = OFF_ABT + NL * NC2 / 2; // f16 [992][256]
constexpr int OFF_SA  = OFF_MH + NL * NC / 2;
constexpr int OFF_SB  = OFF_SA + 1024;
constexpr int OFF_INV = OFF_SA + 2048;
constexpr int TSTRIDE = OFF_SA + 3072;        // 2,860,032 f -> 91.5 MB total

__device__ __forceinline__ void gload16(const void* g, void* l) {
    __builtin_amdgcn_global_load_lds(
        (const __attribute__((address_space(1))) unsigned int*)g,
        (__attribute__((address_space(3))) unsigned int*)(unsigned long)(uintptr_t)l,
        16, 0, 0);
}

// ---------------- K1: Mh = f16(a*b), per-pixel squared norms ----------------
__global__ __launch_bounds__(256) void k_prep(const float* __restrict__ x,
                                              float* __restrict__ ws) {
    const int blk = blockIdx.x;       // t*NL + l
    const int t = blk / NL;
    const int l = blk - t * NL;
    const int s = t >> 1, o = t & 1;
    int aoff, boff;
    if (o == 0) {  // lr grid (31,32)
        const int lh = l >> 5, lw = l & 31;
        aoff = ((s * 32 + lh) * 32 + lw) * NC;
        boff = ((s * 32 + lh + 1) * 32 + lw) * NC;
    } else {       // tb grid (32,31)
        const int lh = l / 31, lw = l - lh * 31;
        aoff = ((s * 32 + lh) * 32 + lw + 1) * NC;
        boff = ((s * 32 + lh) * 32 + lw) * NC;
    }
    float* wst = ws + (size_t)t * TSTRIDE;
    const int c = threadIdx.x;
    const float av = x[aoff + c];
    const float bv = x[boff + c];
    ((_Float16*)(wst + OFF_MH))[l * NC + c] = (_Float16)(av * bv);
    float ra = av * av, rb = bv * bv;
#pragma unroll
    for (int off = 32; off > 0; off >>= 1) {
        ra += __shfl_down(ra, off);
        rb += __shfl_down(rb, off);
    }
    __shared__ float shA[4], shB[4];
    const int wave = threadIdx.x >> 6, lane = threadIdx.x & 63;
    if (lane == 0) { shA[wave] = ra; shB[wave] = rb; }
    __syncthreads();
    if (threadIdx.x == 0) {
        wst[OFF_SA + l] = shA[0] + shA[1] + shA[2] + shA[3];
        wst[OFF_SB + l] = shB[0] + shB[1] + shB[2] + shB[3];
    }
}

// ---------------- K1b: ABt[c][l] (f16) via 32x32 LDS transpose ----------------
__global__ __launch_bounds__(256) void k_abt(const float* __restrict__ x,
                                             float* __restrict__ ws) {
    const int t = blockIdx.z, s = t >> 1, o = t & 1;
    const int c0 = blockIdx.y * 32;   // 0..480
    const int l0 = blockIdx.x * 32;   // 0..960
    float* wst = ws + (size_t)t * TSTRIDE;
    _Float16* __restrict__ ABt = (_Float16*)(wst + OFF_ABT);
    __shared__ float T[32 * 33];
    const int tid = threadIdx.x;
    const bool isB = (c0 >= 256);
    const int cb = isB ? c0 - 256 : c0;
    {
        const int li = tid >> 3, cq = tid & 7;
        const int l = l0 + li;
        int xoff;
        if (o == 0) {
            const int lh = l >> 5, lw = l & 31;
            xoff = isB ? ((s * 32 + lh + 1) * 32 + lw) : ((s * 32 + lh) * 32 + lw);
        } else {
            const int lh = l / 31, lw = l - lh * 31;
            xoff = isB ? ((s * 32 + lh) * 32 + lw) : ((s * 32 + lh) * 32 + lw + 1);
        }
        const float4 v = *(const float4*)&x[xoff * NC + cb + cq * 4];
        T[(cq * 4 + 0) * 33 + li] = v.x;
        T[(cq * 4 + 1) * 33 + li] = v.y;
        T[(cq * 4 + 2) * 33 + li] = v.z;
        T[(cq * 4 + 3) * 33 + li] = v.w;
    }
    __syncthreads();
    {
        const int ci = tid >> 3, lq = tid & 7;
        half4h h;
        h.x = (_Float16)T[ci * 33 + lq * 4 + 0];
        h.y = (_Float16)T[ci * 33 + lq * 4 + 1];
        h.z = (_Float16)T[ci * 33 + lq * 4 + 2];
        h.w = (_Float16)T[ci * 33 + lq * 4 + 3];
        *(half4h*)&ABt[(c0 + ci) * NL + l0 + lq * 4] = h;
    }
}

// ---------------- K2: inv from 3x3 box sums of squared norms ----------------
__global__ __launch_bounds__(1024) void k_inv(float* __restrict__ ws) {
    const int t = blockIdx.x;
    const int l = threadIdx.x;
    if (l >= NL) return;
    const int o = t & 1;
    const int Hp = o ? 32 : 31, Wp = o ? 31 : 32;
    float* wst = ws + (size_t)t * TSTRIDE;
    const int h = l / Wp, w = l - h * Wp;
    float na2 = 0.0f, nb2 = 0.0f;
#pragma unroll
    for (int dh = -1; dh <= 1; ++dh)
#pragma unroll
        for (int dw = -1; dw <= 1; ++dw) {
            const int hh = h + dh, ww = w + dw;
            if ((unsigned)hh < (unsigned)Hp && (unsigned)ww < (unsigned)Wp) {
                const int ll = hh * Wp + ww;
                na2 += wst[OFF_SA + ll];
                nb2 += wst[OFF_SB + ll];
            }
        }
    const float na = fmaxf(sqrtf(na2), 1e-4f);
    const float nb = fmaxf(sqrtf(nb2), 1e-4f);
    wst[OFF_INV + l] = 1.0f / (na * nb);
}

// ---------------- K3: S = Mh Mh^T  (992x992, K=256) MFMA f16 ----------------
__global__ __launch_bounds__(256) void k_gram(float* __restrict__ ws) {
    const int t = blockIdx.z;
    float* wst = ws + (size_t)t * TSTRIDE;
    const _Float16* __restrict__ M = (const _Float16*)(wst + OFF_MH);
    float* __restrict__ S = wst + OFF_S;
    __shared__ __align__(16) _Float16 As[128 * 32];
    __shared__ __align__(16) _Float16 Bs[128 * 32];
    const int tid = threadIdx.x;
    const int i0 = blockIdx.y * 128, j0 = blockIdx.x * 128;
    const int wave = tid >> 6, lane = tid & 63;
    const int wm = wave & 1, wn = wave >> 1;
    const int l15 = lane & 15, quad = lane >> 4;
    floatx4 acc[4][4] = {};
    const int srow = tid >> 2;        // 0..63
    const int scol = (tid & 3) * 8;   // halves
    for (int k0 = 0; k0 < NC; k0 += 32) {
        __syncthreads();
        if (i0 + srow < NL)      gload16(&M[(i0 + srow) * NC + k0 + scol], &As[srow * 32 + scol]);
        if (i0 + 64 + srow < NL) gload16(&M[(i0 + 64 + srow) * NC + k0 + scol], &As[(64 + srow) * 32 + scol]);
        if (j0 + srow < NL)      gload16(&M[(j0 + srow) * NC + k0 + scol], &Bs[srow * 32 + scol]);
        if (j0 + 64 + srow < NL) gload16(&M[(j0 + 64 + srow) * NC + k0 + scol], &Bs[(64 + srow) * 32 + scol]);
        __syncthreads();
        half8 a[4], b[4];
#pragma unroll
        for (int mt = 0; mt < 4; ++mt) a[mt] = *(const half8*)&As[(wm * 64 + mt * 16 + l15) * 32 + quad * 8];
#pragma unroll
        for (int nt = 0; nt < 4; ++nt) b[nt] = *(const half8*)&Bs[(wn * 64 + nt * 16 + l15) * 32 + quad * 8];
#pragma unroll
        for (int mt = 0; mt < 4; ++mt)
#pragma unroll
            for (int nt = 0; nt < 4; ++nt)
                acc[mt][nt] = __builtin_amdgcn_mfma_f32_16x16x32_f16(a[mt], b[nt], acc[mt][nt], 0, 0, 0);
    }
#pragma unroll
    for (int mt = 0; mt < 4; ++mt)
#pragma unroll
        for (int nt = 0; nt < 4; ++nt)
#pragma unroll
            for (int r = 0; r < 4; ++r) {
                const int row = i0 + wm * 64 + mt * 16 + quad * 4 + r;
                const int col = j0 + wn * 64 + nt * 16 + l15;
                if (row < NL && col < NL) S[row * NL + col] = acc[mt][nt][r];
            }
}

// ---------------- K4: G (9-shift band sum of S) -> softmax -> Ph (f16) ------
__global__ __launch_bounds__(256) void k_softmax(float* __restrict__ ws) {
    const int blk = blockIdx.x;       // t*NL + l1
    const int t = blk / NL;
    const int l1 = blk - t * NL;
    const int o = t & 1;
    const int Hp = o ? 32 : 31, Wp = o ? 31 : 32;
    float* wst = ws + (size_t)t * TSTRIDE;
    const float* __restrict__ S = wst + OFF_S;
    const float* __restrict__ inv = wst + OFF_INV;
    _Float16* __restrict__ Ph = (_Float16*)(wst + OFF_PH);
    const int h1 = l1 / Wp, w1 = l1 - h1 * Wp;
    const float inv1 = inv[l1] * 10.0f;
    float lg[4];
    float mx = -3.0e38f;
#pragma unroll
    for (int j = 0; j < 4; ++j) {
        const int l2 = threadIdx.x + j * 256;
        if (l2 < NL) {
            const int h2 = l2 / Wp, w2 = l2 - h2 * Wp;
            float G = 0.0f;
#pragma unroll
            for (int dh = -1; dh <= 1; ++dh)
#pragma unroll
                for (int dw = -1; dw <= 1; ++dw) {
                    const bool ok = (unsigned)(h1 + dh) < (unsigned)Hp &&
                                    (unsigned)(w1 + dw) < (unsigned)Wp &&
                                    (unsigned)(h2 + dh) < (unsigned)Hp &&
                                    (unsigned)(w2 + dw) < (unsigned)Wp;
                    if (ok) {
                        const int d = dh * Wp + dw;
                        G += S[(l1 + d) * NL + (l2 + d)];
                    }
                }
            lg[j] = G * inv1 * inv[l2];
            mx = fmaxf(mx, lg[j]);
        } else {
            lg[j] = -3.0e38f;
        }
    }
    __shared__ float red[4];
    const int wave = threadIdx.x >> 6, lane = threadIdx.x & 63;
#pragma unroll
    for (int off = 32; off > 0; off >>= 1) mx = fmaxf(mx, __shfl_down(mx, off));
    if (lane == 0) red[wave] = mx;
    __syncthreads();
    mx = fmaxf(fmaxf(red[0], red[1]), fmaxf(red[2], red[3]));
    __syncthreads();
    float e[4];
    float sum = 0.0f;
#pragma unroll
    for (int j = 0; j < 4; ++j) {
        const int l2 = threadIdx.x + j * 256;
        e[j] = __expf(lg[j] - mx);
        if (l2 < NL) sum += e[j];
    }
#pragma unroll
    for (int off = 32; off > 0; off >>= 1) sum += __shfl_down(sum, off);
    if (lane == 0) red[wave] = sum;
    __syncthreads();
    sum = red[0] + red[1] + red[2] + red[3];
    const float rs = 1.0f / sum;
#pragma unroll
    for (int j = 0; j < 4; ++j) {
        const int l2 = threadIdx.x + j * 256;
        if (l2 < NL) Ph[l1 * NL + l2] = (_Float16)(e[j] * rs);
    }
}

// ---------------- K5: Wh = 9-shift band sum of Ph (f16) ----------------
__global__ __launch_bounds__(256) void k_blur(float* __restrict__ ws) {
    const int blk = blockIdx.x;       // t*NL + m
    const int t = blk / NL;
    const int m = blk - t * NL;
    const int o = t & 1;
    const int Hp = o ? 32 : 31, Wp = o ? 31 : 32;
    float* wst = ws + (size_t)t * TSTRIDE;
    const _Float16* __restrict__ Ph = (const _Float16*)(wst + OFF_PH);
    _Float16* __restrict__ Wh = (_Float16*)(wst + OFF_WH);
    const int tid = threadIdx.x;
    if (tid >= 248) return;
    const int hm = m / Wp, wm = m - hm * Wp;
    int hp4[4], wp4[4];
#pragma unroll
    for (int jj = 0; jj < 4; ++jj) {
        const int lp = tid * 4 + jj;
        hp4[jj] = lp / Wp;
        wp4[jj] = lp - hp4[jj] * Wp;
    }
    float acc[4] = {};
#pragma unroll
    for (int dh = -1; dh <= 1; ++dh) {
        if ((unsigned)(hm - dh) >= (unsigned)Hp) continue;
#pragma unroll
        for (int dw = -1; dw <= 1; ++dw) {
            if ((unsigned)(wm - dw) >= (unsigned)Wp) continue;
            const int d = dh * Wp + dw;
            const _Float16* row = Ph + (m - d) * NL - d;
#pragma unroll
            for (int jj = 0; jj < 4; ++jj) {
                if ((unsigned)(hp4[jj] - dh) < (unsigned)Hp &&
                    (unsigned)(wp4[jj] - dw) < (unsigned)Wp)
                    acc[jj] += (float)row[tid * 4 + jj];
            }
        }
    }
    half4h h;
    h.x = (_Float16)acc[0]; h.y = (_Float16)acc[1];
    h.z = (_Float16)acc[2]; h.w = (_Float16)acc[3];
    *(half4h*)&Wh[m * NL + tid * 4] = h;
}

// ---------------- K6: Y = Wh @ ABt^T (992x512, K=992) MFMA f16 ----------------
__global__ __launch_bounds__(256) void k_recon(float* __restrict__ ws) {
    const int t = blockIdx.z;
    float* wst = ws + (size_t)t * TSTRIDE;
    const _Float16* __restrict__ Wm = (const _Float16*)(wst + OFF_WH);
    const _Float16* __restrict__ ABt = (const _Float16*)(wst + OFF_ABT);
    float* __restrict__ Y = wst + OFF_Y;
    __shared__ __align__(16) _Float16 As[128 * 32];
    __shared__ __align__(16) _Float16 Bs[128 * 32];
    const int tid = threadIdx.x;
    const int i0 = blockIdx.y * 128, j0 = blockIdx.x * 128;
    const int wave = tid >> 6, lane = tid & 63;
    const int wm = wave & 1, wn = wave >> 1;
    const int l15 = lane & 15, quad = lane >> 4;
    floatx4 acc[4][4] = {};
    const int srow = tid >> 2;
    const int scol = (tid & 3) * 8;
    for (int k0 = 0; k0 < NL; k0 += 32) {   // 31 exact iterations
        __syncthreads();
        if (i0 + srow < NL)      gload16(&Wm[(i0 + srow) * NL + k0 + scol], &As[srow * 32 + scol]);
        if (i0 + 64 + srow < NL) gload16(&Wm[(i0 + 64 + srow) * NL + k0 + scol], &As[(64 + srow) * 32 + scol]);
        gload16(&ABt[(j0 + srow) * NL + k0 + scol], &Bs[srow * 32 + scol]);
        gload16(&ABt[(j0 + 64 + srow) * NL + k0 + scol], &Bs[(64 + srow) * 32 + scol]);
        __syncthreads();
        half8 a[4], b[4];
#pragma unroll
        for (int mt = 0; mt < 4; ++mt) a[mt] = *(const half8*)&As[(wm * 64 + mt * 16 + l15) * 32 + quad * 8];
#pragma unroll
        for (int nt = 0; nt < 4; ++nt) b[nt] = *(const half8*)&Bs[(wn * 64 + nt * 16 + l15) * 32 + quad * 8];
#pragma unroll
        for (int mt = 0; mt < 4; ++mt)
#pragma unroll
            for (int nt = 0; nt < 4; ++nt)
                acc[mt][nt] = __builtin_amdgcn_mfma_f32_16x16x32_f16(a[mt], b[nt], acc[mt][nt], 0, 0, 0);
    }
#pragma unroll
    for (int mt = 0; mt < 4; ++mt)
#pragma unroll
        for (int nt = 0; nt < 4; ++nt)
#pragma unroll
            for (int r = 0; r < 4; ++r) {
                const int row = i0 + wm * 64 + mt * 16 + quad * 4 + r;
                const int col = j0 + wn * 64 + nt * 16 + l15;
                if (row < NL) Y[row * NC2 + col] = acc[mt][nt][r];
            }
}

// ---------------- K7: seam combine -> out ----------------
__global__ __launch_bounds__(256) void k_combine(float* __restrict__ out,
                                                 const float* __restrict__ ws) {
    const int idx = blockIdx.x;          // s*1024 + h*32 + w
    const int s = idx >> 10;
    const int hw = idx & 1023;
    const int h = hw >> 5, w = hw & 31;
    const int c = threadIdx.x;
    const float* Ylr = ws + (size_t)(2 * s) * TSTRIDE + OFF_Y;
    const float* Ytb = ws + (size_t)(2 * s + 1) * TSTRIDE + OFF_Y;
    float v = 0.0f;
    if (h < 31) v += Ylr[(h * 32 + w) * NC2 + NC + c] * (h == 0 ? 1.0f : 0.5f);
    if (h >= 1) v += Ylr[((h - 1) * 32 + w) * NC2 + c] * (h == 31 ? 1.0f : 0.5f);
    if (w < 31) v += Ytb[(h * 31 + w) * NC2 + c] * (w == 0 ? 1.0f : 0.5f);
    if (w >= 1) v += Ytb[(h * 31 + (w - 1)) * NC2 + NC + c] * (w == 31 ? 1.0f : 0.5f);
    out[(size_t)idx * NC + c] = v * 0.5f;
}

extern "C" void kernel_launch(void* const* d_in, const int* in_sizes, int n_in,
                              void* d_out, int out_size, void* d_ws, size_t ws_size,
                              hipStream_t stream) {
    const float* x = (const float*)d_in[0];
    float* out = (float*)d_out;
    float* ws = (float*)d_ws;    // 8*TSTRIDE*4 = 91.5 MB

    hipLaunchKernelGGL(k_prep,    dim3(8 * NL),    dim3(256),  0, stream, x, ws);
    hipLaunchKernelGGL(k_abt,     dim3(31, 16, 8), dim3(256),  0, stream, x, ws);
    hipLaunchKernelGGL(k_inv,     dim3(8),         dim3(1024), 0, stream, ws);
    hipLaunchKernelGGL(k_gram,    dim3(8, 8, 8),   dim3(256),  0, stream, ws);
    hipLaunchKernelGGL(k_softmax, dim3(8 * NL),    dim3(256),  0, stream, ws);
    hipLaunchKernelGGL(k_blur,    dim3(8 * NL),    dim3(256),  0, stream, ws);
    hipLaunchKernelGGL(k_recon,   dim3(4, 8, 8),   dim3(256),  0, stream, ws);
    hipLaunchKernelGGL(k_combine, dim3(4096),      dim3(256),  0, stream, out, ws);
}

// Round 3
// 196.287 us; speedup vs baseline: 1.9888x; 1.1119x over previous
//
#include <hip/hip_runtime.h>

// B=4, H=W=32, C=256. 8 tasks (sample x orientation), grid L=992 each.
// Pipeline: Mh=f16(a*b) -> S = Mh Mh^T (MFMA, f16 out)
//   Sw = w-band(S) [k_bandw] ; G = h-band(Sw) fused in softmax -> Ph (f16)
//   Pw = w-band(Ph) [k_bandw] ; Wh = h-band(Pw) [k_blur]
//   Y = Wh @ ABt^T (MFMA f16, fp32 out) -> seam combine.
// Band separability: validity [h-ok(dh)]*[w-ok(dw)] factors; shift d=dh*Wp+dw.

typedef _Float16 half8 __attribute__((ext_vector_type(8)));
typedef _Float16 half4h __attribute__((ext_vector_type(4)));
typedef float floatx4 __attribute__((ext_vector_type(4)));

constexpr int NL = 992, NC = 256, NC2 = 512;
constexpr int NLL = NL * NL;
// float-granular per-task offsets
constexpr int OFF_B0  = 0;                     // f16 LxL: S, later Pw
constexpr int OFF_B1  = NLL / 2;               // f16 LxL: Sw, later Wh
constexpr int OFF_B2  = NLL;                   // f16 LxL: P
constexpr int OFF_Y   = NLL + NLL / 2;         // f32 [992][512]
constexpr int OFF_ABT = OFF_Y + NL * NC2;      // f16 [512][992]
constexpr int OFF_MH  = OFF_ABT + NL * NC2 / 2;// f16 [992][256]
constexpr int OFF_SA  = OFF_MH + NL * NC / 2;
constexpr int OFF_SB  = OFF_SA + 1024;
constexpr int OFF_INV = OFF_SA + 2048;
constexpr int TSTRIDE = OFF_SA + 3072;         // 2,368,000 f -> 75.8 MB total

__device__ __forceinline__ void gload16(const void* g, void* l) {
    __builtin_amdgcn_global_load_lds(
        (const __attribute__((address_space(1))) unsigned int*)g,
        (__attribute__((address_space(3))) unsigned int*)(unsigned long)(uintptr_t)l,
        16, 0, 0);
}

// ---------------- K1: Mh = f16(a*b), per-pixel squared norms ----------------
__global__ __launch_bounds__(256) void k_prep(const float* __restrict__ x,
                                              float* __restrict__ ws) {
    const int blk = blockIdx.x;       // t*NL + l
    const int t = blk / NL;
    const int l = blk - t * NL;
    const int s = t >> 1, o = t & 1;
    int aoff, boff;
    if (o == 0) {  // lr grid (31,32)
        const int lh = l >> 5, lw = l & 31;
        aoff = ((s * 32 + lh) * 32 + lw) * NC;
        boff = ((s * 32 + lh + 1) * 32 + lw) * NC;
    } else {       // tb grid (32,31)
        const int lh = l / 31, lw = l - lh * 31;
        aoff = ((s * 32 + lh) * 32 + lw + 1) * NC;
        boff = ((s * 32 + lh) * 32 + lw) * NC;
    }
    float* wst = ws + (size_t)t * TSTRIDE;
    const int c = threadIdx.x;
    const float av = x[aoff + c];
    const float bv = x[boff + c];
    ((_Float16*)(wst + OFF_MH))[l * NC + c] = (_Float16)(av * bv);
    float ra = av * av, rb = bv * bv;
#pragma unroll
    for (int off = 32; off > 0; off >>= 1) {
        ra += __shfl_down(ra, off);
        rb += __shfl_down(rb, off);
    }
    __shared__ float shA[4], shB[4];
    const int wave = threadIdx.x >> 6, lane = threadIdx.x & 63;
    if (lane == 0) { shA[wave] = ra; shB[wave] = rb; }
    __syncthreads();
    if (threadIdx.x == 0) {
        wst[OFF_SA + l] = shA[0] + shA[1] + shA[2] + shA[3];
        wst[OFF_SB + l] = shB[0] + shB[1] + shB[2] + shB[3];
    }
}

// ---------------- K1b: ABt[c][l] (f16) via 32x32 LDS transpose ----------------
__global__ __launch_bounds__(256) void k_abt(const float* __restrict__ x,
                                             float* __restrict__ ws) {
    const int t = blockIdx.z, s = t >> 1, o = t & 1;
    const int c0 = blockIdx.y * 32;
    const int l0 = blockIdx.x * 32;
    float* wst = ws + (size_t)t * TSTRIDE;
    _Float16* __restrict__ ABt = (_Float16*)(wst + OFF_ABT);
    __shared__ float T[32 * 33];
    const int tid = threadIdx.x;
    const bool isB = (c0 >= 256);
    const int cb = isB ? c0 - 256 : c0;
    {
        const int li = tid >> 3, cq = tid & 7;
        const int l = l0 + li;
        int xoff;
        if (o == 0) {
            const int lh = l >> 5, lw = l & 31;
            xoff = isB ? ((s * 32 + lh + 1) * 32 + lw) : ((s * 32 + lh) * 32 + lw);
        } else {
            const int lh = l / 31, lw = l - lh * 31;
            xoff = isB ? ((s * 32 + lh) * 32 + lw) : ((s * 32 + lh) * 32 + lw + 1);
        }
        const float4 v = *(const float4*)&x[xoff * NC + cb + cq * 4];
        T[(cq * 4 + 0) * 33 + li] = v.x;
        T[(cq * 4 + 1) * 33 + li] = v.y;
        T[(cq * 4 + 2) * 33 + li] = v.z;
        T[(cq * 4 + 3) * 33 + li] = v.w;
    }
    __syncthreads();
    {
        const int ci = tid >> 3, lq = tid & 7;
        half4h h;
        h.x = (_Float16)T[ci * 33 + lq * 4 + 0];
        h.y = (_Float16)T[ci * 33 + lq * 4 + 1];
        h.z = (_Float16)T[ci * 33 + lq * 4 + 2];
        h.w = (_Float16)T[ci * 33 + lq * 4 + 3];
        *(half4h*)&ABt[(c0 + ci) * NL + l0 + lq * 4] = h;
    }
}

// ---------------- K2: inv from 3x3 box sums of squared norms ----------------
__global__ __launch_bounds__(1024) void k_inv(float* __restrict__ ws) {
    const int t = blockIdx.x;
    const int l = threadIdx.x;
    if (l >= NL) return;
    const int o = t & 1;
    const int Hp = o ? 32 : 31, Wp = o ? 31 : 32;
    float* wst = ws + (size_t)t * TSTRIDE;
    const int h = l / Wp, w = l - h * Wp;
    float na2 = 0.0f, nb2 = 0.0f;
#pragma unroll
    for (int dh = -1; dh <= 1; ++dh)
#pragma unroll
        for (int dw = -1; dw <= 1; ++dw) {
            const int hh = h + dh, ww = w + dw;
            if ((unsigned)hh < (unsigned)Hp && (unsigned)ww < (unsigned)Wp) {
                const int ll = hh * Wp + ww;
                na2 += wst[OFF_SA + ll];
                nb2 += wst[OFF_SB + ll];
            }
        }
    const float na = fmaxf(sqrtf(na2), 1e-4f);
    const float nb = fmaxf(sqrtf(nb2), 1e-4f);
    wst[OFF_INV + l] = 1.0f / (na * nb);
}

// ---------------- K3: S = Mh Mh^T (992x992, K=256) MFMA f16, f16 out ----------
__global__ __launch_bounds__(256) void k_gram(float* __restrict__ ws) {
    const int t = blockIdx.z;
    float* wst = ws + (size_t)t * TSTRIDE;
    const _Float16* __restrict__ M = (const _Float16*)(wst + OFF_MH);
    _Float16* __restrict__ S = (_Float16*)(wst + OFF_B0);
    __shared__ __align__(16) _Float16 As[128 * 32];
    __shared__ __align__(16) _Float16 Bs[128 * 32];
    const int tid = threadIdx.x;
    const int i0 = blockIdx.y * 128, j0 = blockIdx.x * 128;
    const int wave = tid >> 6, lane = tid & 63;
    const int wm = wave & 1, wn = wave >> 1;
    const int l15 = lane & 15, quad = lane >> 4;
    floatx4 acc[4][4] = {};
    const int srow = tid >> 2;
    const int scol = (tid & 3) * 8;
    for (int k0 = 0; k0 < NC; k0 += 32) {
        __syncthreads();
        if (i0 + srow < NL)      gload16(&M[(i0 + srow) * NC + k0 + scol], &As[srow * 32 + scol]);
        if (i0 + 64 + srow < NL) gload16(&M[(i0 + 64 + srow) * NC + k0 + scol], &As[(64 + srow) * 32 + scol]);
        if (j0 + srow < NL)      gload16(&M[(j0 + srow) * NC + k0 + scol], &Bs[srow * 32 + scol]);
        if (j0 + 64 + srow < NL) gload16(&M[(j0 + 64 + srow) * NC + k0 + scol], &Bs[(64 + srow) * 32 + scol]);
        __syncthreads();
        half8 a[4], b[4];
#pragma unroll
        for (int mt = 0; mt < 4; ++mt) a[mt] = *(const half8*)&As[(wm * 64 + mt * 16 + l15) * 32 + quad * 8];
#pragma unroll
        for (int nt = 0; nt < 4; ++nt) b[nt] = *(const half8*)&Bs[(wn * 64 + nt * 16 + l15) * 32 + quad * 8];
#pragma unroll
        for (int mt = 0; mt < 4; ++mt)
#pragma unroll
            for (int nt = 0; nt < 4; ++nt)
                acc[mt][nt] = __builtin_amdgcn_mfma_f32_16x16x32_f16(a[mt], b[nt], acc[mt][nt], 0, 0, 0);
    }
#pragma unroll
    for (int mt = 0; mt < 4; ++mt)
#pragma unroll
        for (int nt = 0; nt < 4; ++nt)
#pragma unroll
            for (int r = 0; r < 4; ++r) {
                const int row = i0 + wm * 64 + mt * 16 + quad * 4 + r;
                const int col = j0 + wn * 64 + nt * 16 + l15;
                if (row < NL && col < NL) S[row * NL + col] = (_Float16)acc[mt][nt][r];
            }
}

// -------- K_bandw: dst[r,c] = src[r,c] + diag-neighbors with w-validity --------
// dst[r,c] = src[r,c] + [w_r>0 & w_c>0] src[r-1,c-1] + [w_r+1<Wp & w_c+1<Wp] src[r+1,c+1]
__global__ __launch_bounds__(256) void k_bandw(float* __restrict__ ws, int srcOff, int dstOff) {
    const int blk = blockIdx.x;       // t*NL + r
    const int t = blk / NL;
    const int r = blk - t * NL;
    const int o = t & 1;
    const int Wp = o ? 31 : 32;
    const unsigned MAGIC = o ? 33826u : 32768u;   // x/Wp = (x*MAGIC)>>20 for x<1024
    float* wst = ws + (size_t)t * TSTRIDE;
    const _Float16* __restrict__ src = (const _Float16*)(wst + srcOff);
    _Float16* __restrict__ dst = (_Float16*)(wst + dstOff);
    const int tid = threadIdx.x;
    if (tid >= 248) return;
    const int w1 = r - (int)((r * MAGIC) >> 20) * Wp;
    const bool okm = (w1 > 0), okp = (w1 + 1 < Wp);
    const _Float16* s0 = src + r * NL;
    half4h outv;
#pragma unroll
    for (int jj = 0; jj < 4; ++jj) {
        const int c = tid * 4 + jj;
        const int w2 = c - (int)((c * MAGIC) >> 20) * Wp;
        float v = (float)s0[c];
        if (okm && w2 > 0) v += (float)s0[c - NL - 1];
        if (okp && w2 + 1 < Wp) v += (float)s0[c + NL + 1];
        outv[jj] = (_Float16)v;
    }
    *(half4h*)&dst[r * NL + tid * 4] = outv;
}

// ---------------- K4: G = h-band(Sw) -> softmax -> Ph (f16) ----------------
__global__ __launch_bounds__(256) void k_softmax(float* __restrict__ ws) {
    const int blk = blockIdx.x;       // t*NL + l1
    const int t = blk / NL;
    const int l1 = blk - t * NL;
    const int o = t & 1;
    const int Hp = o ? 32 : 31, Wp = o ? 31 : 32;
    const unsigned MAGIC = o ? 33826u : 32768u;
    float* wst = ws + (size_t)t * TSTRIDE;
    const _Float16* __restrict__ Sw = (const _Float16*)(wst + OFF_B1);
    const float* __restrict__ inv = wst + OFF_INV;
    _Float16* __restrict__ Ph = (_Float16*)(wst + OFF_B2);
    const int h1 = (int)((l1 * MAGIC) >> 20);
    const bool okm = (h1 > 0), okp = (h1 + 1 < Hp);
    const float inv1 = inv[l1] * 10.0f;
    const _Float16* s0 = Sw + l1 * NL;
    constexpr int DSH = 992 + 1;      // not used; shift is Wp*(NL+1)
    (void)DSH;
    const int shp = Wp * (NL + 1);
    float lg[4];
    float mx = -3.0e38f;
#pragma unroll
    for (int j = 0; j < 4; ++j) {
        const int l2 = threadIdx.x + j * 256;
        if (l2 < NL) {
            const int h2 = (int)((l2 * MAGIC) >> 20);
            float G = (float)s0[l2];
            if (okm && h2 > 0) G += (float)s0[l2 - shp];
            if (okp && h2 + 1 < Hp) G += (float)s0[l2 + shp];
            lg[j] = G * inv1 * inv[l2];
            mx = fmaxf(mx, lg[j]);
        } else {
            lg[j] = -3.0e38f;
        }
    }
    __shared__ float red[4];
    const int wave = threadIdx.x >> 6, lane = threadIdx.x & 63;
#pragma unroll
    for (int off = 32; off > 0; off >>= 1) mx = fmaxf(mx, __shfl_down(mx, off));
    if (lane == 0) red[wave] = mx;
    __syncthreads();
    mx = fmaxf(fmaxf(red[0], red[1]), fmaxf(red[2], red[3]));
    __syncthreads();
    float e[4];
    float sum = 0.0f;
#pragma unroll
    for (int j = 0; j < 4; ++j) {
        const int l2 = threadIdx.x + j * 256;
        e[j] = __expf(lg[j] - mx);
        if (l2 < NL) sum += e[j];
    }
#pragma unroll
    for (int off = 32; off > 0; off >>= 1) sum += __shfl_down(sum, off);
    if (lane == 0) red[wave] = sum;
    __syncthreads();
    sum = red[0] + red[1] + red[2] + red[3];
    const float rs = 1.0f / sum;
#pragma unroll
    for (int j = 0; j < 4; ++j) {
        const int l2 = threadIdx.x + j * 256;
        if (l2 < NL) Ph[l1 * NL + l2] = (_Float16)(e[j] * rs);
    }
}

// ---------------- K5: Wh = h-band(Pw) (f16) ----------------
// Wh[m,c] = Pw[m,c] + [hm>0 & hc>0] Pw[m-Wp,c-Wp] + [hm+1<Hp & hc+1<Hp] Pw[m+Wp,c+Wp]
__global__ __launch_bounds__(256) void k_blur(float* __restrict__ ws) {
    const int blk = blockIdx.x;       // t*NL + m
    const int t = blk / NL;
    const int m = blk - t * NL;
    const int o = t & 1;
    const int Hp = o ? 32 : 31, Wp = o ? 31 : 32;
    const unsigned MAGIC = o ? 33826u : 32768u;
    float* wst = ws + (size_t)t * TSTRIDE;
    const _Float16* __restrict__ Pw = (const _Float16*)(wst + OFF_B0);
    _Float16* __restrict__ Wh = (_Float16*)(wst + OFF_B1);
    const int tid = threadIdx.x;
    if (tid >= 248) return;
    const int hm = (int)((m * MAGIC) >> 20);
    const bool okm = (hm > 0), okp = (hm + 1 < Hp);
    const int shp = Wp * (NL + 1);
    const _Float16* p0 = Pw + m * NL;
    half4h outv;
#pragma unroll
    for (int jj = 0; jj < 4; ++jj) {
        const int c = tid * 4 + jj;
        const int hc = (int)((c * MAGIC) >> 20);
        float v = (float)p0[c];
        if (okm && hc > 0) v += (float)p0[c - shp];
        if (okp && hc + 1 < Hp) v += (float)p0[c + shp];
        outv[jj] = (_Float16)v;
    }
    *(half4h*)&Wh[m * NL + tid * 4] = outv;
}

// ---------------- K6: Y = Wh @ ABt^T (992x512, K=992) MFMA f16 ----------------
__global__ __launch_bounds__(256) void k_recon(float* __restrict__ ws) {
    const int t = blockIdx.z;
    float* wst = ws + (size_t)t * TSTRIDE;
    const _Float16* __restrict__ Wm = (const _Float16*)(wst + OFF_B1);
    const _Float16* __restrict__ ABt = (const _Float16*)(wst + OFF_ABT);
    float* __restrict__ Y = wst + OFF_Y;
    __shared__ __align__(16) _Float16 As[128 * 32];
    __shared__ __align__(16) _Float16 Bs[128 * 32];
    const int tid = threadIdx.x;
    const int i0 = blockIdx.y * 128, j0 = blockIdx.x * 128;
    const int wave = tid >> 6, lane = tid & 63;
    const int wm = wave & 1, wn = wave >> 1;
    const int l15 = lane & 15, quad = lane >> 4;
    floatx4 acc[4][4] = {};
    const int srow = tid >> 2;
    const int scol = (tid & 3) * 8;
    for (int k0 = 0; k0 < NL; k0 += 32) {   // 31 exact iterations
        __syncthreads();
        if (i0 + srow < NL)      gload16(&Wm[(i0 + srow) * NL + k0 + scol], &As[srow * 32 + scol]);
        if (i0 + 64 + srow < NL) gload16(&Wm[(i0 + 64 + srow) * NL + k0 + scol], &As[(64 + srow) * 32 + scol]);
        gload16(&ABt[(j0 + srow) * NL + k0 + scol], &Bs[srow * 32 + scol]);
        gload16(&ABt[(j0 + 64 + srow) * NL + k0 + scol], &Bs[(64 + srow) * 32 + scol]);
        __syncthreads();
        half8 a[4], b[4];
#pragma unroll
        for (int mt = 0; mt < 4; ++mt) a[mt] = *(const half8*)&As[(wm * 64 + mt * 16 + l15) * 32 + quad * 8];
#pragma unroll
        for (int nt = 0; nt < 4; ++nt) b[nt] = *(const half8*)&Bs[(wn * 64 + nt * 16 + l15) * 32 + quad * 8];
#pragma unroll
        for (int mt = 0; mt < 4; ++mt)
#pragma unroll
            for (int nt = 0; nt < 4; ++nt)
                acc[mt][nt] = __builtin_amdgcn_mfma_f32_16x16x32_f16(a[mt], b[nt], acc[mt][nt], 0, 0, 0);
    }
#pragma unroll
    for (int mt = 0; mt < 4; ++mt)
#pragma unroll
        for (int nt = 0; nt < 4; ++nt)
#pragma unroll
            for (int r = 0; r < 4; ++r) {
                const int row = i0 + wm * 64 + mt * 16 + quad * 4 + r;
                const int col = j0 + wn * 64 + nt * 16 + l15;
                if (row < NL) Y[row * NC2 + col] = acc[mt][nt][r];
            }
}

// ---------------- K7: seam combine -> out ----------------
__global__ __launch_bounds__(256) void k_combine(float* __restrict__ out,
                                                 const float* __restrict__ ws) {
    const int idx = blockIdx.x;          // s*1024 + h*32 + w
    const int s = idx >> 10;
    const int hw = idx & 1023;
    const int h = hw >> 5, w = hw & 31;
    const int c = threadIdx.x;
    const float* Ylr = ws + (size_t)(2 * s) * TSTRIDE + OFF_Y;
    const float* Ytb = ws + (size_t)(2 * s + 1) * TSTRIDE + OFF_Y;
    float v = 0.0f;
    if (h < 31) v += Ylr[(h * 32 + w) * NC2 + NC + c] * (h == 0 ? 1.0f : 0.5f);
    if (h >= 1) v += Ylr[((h - 1) * 32 + w) * NC2 + c] * (h == 31 ? 1.0f : 0.5f);
    if (w < 31) v += Ytb[(h * 31 + w) * NC2 + c] * (w == 0 ? 1.0f : 0.5f);
    if (w >= 1) v += Ytb[(h * 31 + (w - 1)) * NC2 + NC + c] * (w == 31 ? 1.0f : 0.5f);
    out[(size_t)idx * NC + c] = v * 0.5f;
}

extern "C" void kernel_launch(void* const* d_in, const int* in_sizes, int n_in,
                              void* d_out, int out_size, void* d_ws, size_t ws_size,
                              hipStream_t stream) {
    const float* x = (const float*)d_in[0];
    float* out = (float*)d_out;
    float* ws = (float*)d_ws;    // 8*TSTRIDE*4 = 75.8 MB

    hipLaunchKernelGGL(k_prep,    dim3(8 * NL),    dim3(256),  0, stream, x, ws);
    hipLaunchKernelGGL(k_abt,     dim3(31, 16, 8), dim3(256),  0, stream, x, ws);
    hipLaunchKernelGGL(k_inv,     dim3(8),         dim3(1024), 0, stream, ws);
    hipLaunchKernelGGL(k_gram,    dim3(8, 8, 8),   dim3(256),  0, stream, ws);
    hipLaunchKernelGGL(k_bandw,   dim3(8 * NL),    dim3(256),  0, stream, ws, OFF_B0, OFF_B1); // S->Sw
    hipLaunchKernelGGL(k_softmax, dim3(8 * NL),    dim3(256),  0, stream, ws);
    hipLaunchKernelGGL(k_bandw,   dim3(8 * NL),    dim3(256),  0, stream, ws, OFF_B2, OFF_B0); // P->Pw
    hipLaunchKernelGGL(k_blur,    dim3(8 * NL),    dim3(256),  0, stream, ws);
    hipLaunchKernelGGL(k_recon,   dim3(4, 8, 8),   dim3(256),  0, stream, ws);
    hipLaunchKernelGGL(k_combine, dim3(4096),      dim3(256),  0, stream, out, ws);
}